// Round 1
// baseline (83.115 us; speedup 1.0000x reference)
//
#include <hip/hip_runtime.h>

// TaskSpecificReadout: out[n,c] = sum_d x[n,d] * W[tasks[n],c,d] + b[tasks[n],c]
// B=2048, D=1024, T=16, C=128. Strategy: bucket samples by task, then
// per-task register-tiled fp32 GEMM with LDS staging.

constexpr int D_DIM = 1024;
constexpr int C_DIM = 128;
constexpr int T_DIM = 16;
constexpr int STILE = 32;   // samples per block tile
constexpr int CTILE = 32;   // channels per block tile
constexpr int DK    = 64;   // k-chunk staged in LDS
constexpr int LDSPAD = 4;   // row pad (floats) to keep float4 alignment

__global__ void build_index_kernel(const int* __restrict__ tasks, int B,
                                   int* __restrict__ offsets,  // T+1 ints
                                   int* __restrict__ idx) {    // B ints
    __shared__ int cnt[T_DIM];
    __shared__ int cur[T_DIM];
    const int tid = threadIdx.x;
    if (tid < T_DIM) cnt[tid] = 0;
    __syncthreads();
    for (int n = tid; n < B; n += blockDim.x) atomicAdd(&cnt[tasks[n]], 1);
    __syncthreads();
    if (tid == 0) {
        int acc = 0;
        for (int t = 0; t < T_DIM; ++t) { offsets[t] = acc; cur[t] = acc; acc += cnt[t]; }
        offsets[T_DIM] = acc;
    }
    __syncthreads();
    for (int n = tid; n < B; n += blockDim.x) {
        int p = atomicAdd(&cur[tasks[n]], 1);
        idx[p] = n;
    }
}

__device__ inline float dot4(float4 a, float4 b, float acc) {
    acc = fmaf(a.x, b.x, acc);
    acc = fmaf(a.y, b.y, acc);
    acc = fmaf(a.z, b.z, acc);
    acc = fmaf(a.w, b.w, acc);
    return acc;
}

__global__ __launch_bounds__(256) void readout_kernel(
    const float* __restrict__ x,        // [B, D]
    const float* __restrict__ weights,  // [T, C, D]
    const float* __restrict__ biases,   // [T, C]
    const int*   __restrict__ offsets,  // [T+1]
    const int*   __restrict__ idx,      // [B]
    float*       __restrict__ out) {    // [B, C]
    const int t      = blockIdx.z;
    const int base   = offsets[t];
    const int cnt    = offsets[t + 1] - base;
    const int sstart = blockIdx.y * STILE;
    if (sstart >= cnt) return;
    const int cb = blockIdx.x * CTILE;

    __shared__ float xs[STILE][DK + LDSPAD];
    __shared__ float ws[CTILE][DK + LDSPAD];

    const int tid = threadIdx.x;
    const int ty  = tid >> 4;   // 0..15 -> sample rows {ty, ty+16}
    const int tx  = tid & 15;   // 0..15 -> channels     {tx, tx+16}

    float acc00 = 0.f, acc01 = 0.f, acc10 = 0.f, acc11 = 0.f;

    for (int k0 = 0; k0 < D_DIM; k0 += DK) {
        // Stage xs (32 rows x 64 floats) and ws: 512 float4 each, 2 per thread.
        #pragma unroll
        for (int j = 0; j < 2; ++j) {
            const int f  = tid + j * 256;
            const int s  = f >> 4;          // row 0..31
            const int ki = (f & 15) * 4;    // col 0..60 step 4
            float4 v = make_float4(0.f, 0.f, 0.f, 0.f);
            const int r = sstart + s;
            if (r < cnt) {
                const int n = idx[base + r];
                v = *reinterpret_cast<const float4*>(x + (size_t)n * D_DIM + k0 + ki);
            }
            *reinterpret_cast<float4*>(&xs[s][ki]) = v;
            const float4 wv = *reinterpret_cast<const float4*>(
                weights + ((size_t)t * C_DIM + cb + s) * D_DIM + k0 + ki);
            *reinterpret_cast<float4*>(&ws[s][ki]) = wv;
        }
        __syncthreads();

        #pragma unroll
        for (int k4 = 0; k4 < DK / 4; ++k4) {
            const float4 x0 = *reinterpret_cast<const float4*>(&xs[ty     ][k4 * 4]);
            const float4 x1 = *reinterpret_cast<const float4*>(&xs[ty + 16][k4 * 4]);
            const float4 w0 = *reinterpret_cast<const float4*>(&ws[tx     ][k4 * 4]);
            const float4 w1 = *reinterpret_cast<const float4*>(&ws[tx + 16][k4 * 4]);
            acc00 = dot4(x0, w0, acc00);
            acc01 = dot4(x0, w1, acc01);
            acc10 = dot4(x1, w0, acc10);
            acc11 = dot4(x1, w1, acc11);
        }
        __syncthreads();
    }

    // Epilogue: write out + bias. Strided micro-tile mapping.
    #pragma unroll
    for (int i = 0; i < 2; ++i) {
        const int r = sstart + ty + i * 16;
        if (r >= cnt) continue;
        const int n = idx[base + r];
        #pragma unroll
        for (int j = 0; j < 2; ++j) {
            const int c = cb + tx + j * 16;
            float a = (i == 0) ? (j == 0 ? acc00 : acc01)
                               : (j == 0 ? acc10 : acc11);
            out[(size_t)n * C_DIM + c] = a + biases[t * C_DIM + c];
        }
    }
}

extern "C" void kernel_launch(void* const* d_in, const int* in_sizes, int n_in,
                              void* d_out, int out_size, void* d_ws, size_t ws_size,
                              hipStream_t stream) {
    const float* x       = (const float*)d_in[0];
    const int*   tasks   = (const int*)d_in[1];
    const float* weights = (const float*)d_in[2];
    const float* biases  = (const float*)d_in[3];
    float*       out     = (float*)d_out;
    const int B = in_sizes[1];

    int* offsets = (int*)d_ws;        // T+1 ints
    int* idx     = (int*)d_ws + 32;   // B ints

    build_index_kernel<<<1, 256, 0, stream>>>(tasks, B, offsets, idx);

    dim3 grid(C_DIM / CTILE, (B + STILE - 1) / STILE, T_DIM);
    readout_kernel<<<grid, 256, 0, stream>>>(x, weights, biases, offsets, idx, out);
}

// Round 2
// 26.695 us; speedup vs baseline: 3.1135x; 3.1135x over previous
//
#include <hip/hip_runtime.h>
#include <hip/hip_bf16.h>

// TaskSpecificReadout: out[n,c] = sum_d x[n,d] * W[tasks[n],c,d] + b[tasks[n],c]
// B=2048, D=1024, T=16, C=128.
// Round 2: bucket-by-task + compact tile worklist + split-K bf16 MFMA GEMM.
//   prep_kernel: builds per-task index, tile list, and writes out = bias.
//   gemm_kernel: one block per (tile of 32 samples x 128 channels, k-chunk of 128);
//                stages fp32->bf16 into LDS, 16x16x32 bf16 MFMA, atomicAdd into out.

constexpr int D_DIM = 1024;
constexpr int C_DIM = 128;
constexpr int T_DIM = 16;
constexpr int TM     = 32;              // samples per tile
constexpr int KSPLIT = 8;               // k-splits
constexpr int KCH    = D_DIM / KSPLIT;  // 128 k per block
constexpr int LDS_K  = KCH + 8;         // shorts per LDS row (272 B stride, bank-spread)
constexpr int MAX_TILES = 80;           // sum ceil(cnt_t/32) <= 64 + 15 < 80

// ws int layout: [0..16] task offsets, [31] ntiles,
//                [32..111] tile_task, [128..207] tile_m0 (local), [256..2303] idx

typedef __attribute__((ext_vector_type(8))) short bf16x8;
typedef __attribute__((ext_vector_type(4))) float f32x4;

__device__ inline short f2bf(float f) {
    union { __hip_bfloat16 h; short s; } cv;
    cv.h = __float2bfloat16(f);
    return cv.s;
}

__global__ __launch_bounds__(256) void prep_kernel(const int* __restrict__ tasks,
                                                   const float* __restrict__ biases,
                                                   int B,
                                                   int* __restrict__ ws_i,
                                                   float* __restrict__ out) {
    // All blocks: out[n][c] = biases[tasks[n]][c]  (float4-vectorized)
    const int total4 = B * (C_DIM / 4);
    for (int f = blockIdx.x * blockDim.x + threadIdx.x; f < total4;
         f += gridDim.x * blockDim.x) {
        const int n  = f >> 5;      // C/4 = 32 float4 per row
        const int c4 = f & 31;
        const int t  = tasks[n];
        const float4 b = *reinterpret_cast<const float4*>(biases + t * C_DIM + c4 * 4);
        reinterpret_cast<float4*>(out)[f] = b;
    }
    if (blockIdx.x != 0) return;

    // Block 0: count -> prefix + tile list -> scatter
    __shared__ int cnt[T_DIM];
    __shared__ int cur[T_DIM];
    const int tid = threadIdx.x;
    if (tid < T_DIM) cnt[tid] = 0;
    __syncthreads();
    for (int n = tid; n < B; n += 256) atomicAdd(&cnt[tasks[n]], 1);
    __syncthreads();
    if (tid == 0) {
        int acc = 0, nt = 0;
        for (int t = 0; t < T_DIM; ++t) {
            ws_i[t] = acc;
            cur[t]  = acc;
            for (int m0 = 0; m0 < cnt[t]; m0 += TM) {
                ws_i[32 + nt]  = t;
                ws_i[128 + nt] = m0;
                ++nt;
            }
            acc += cnt[t];
        }
        ws_i[16] = acc;
        ws_i[31] = nt;
    }
    __syncthreads();
    for (int n = tid; n < B; n += 256) {
        const int p = atomicAdd(&cur[tasks[n]], 1);
        ws_i[256 + p] = n;
    }
}

__global__ __launch_bounds__(256) void gemm_kernel(const float* __restrict__ x,
                                                   const float* __restrict__ weights,
                                                   const int* __restrict__ ws_i,
                                                   float* __restrict__ out) {
    const int ntiles = ws_i[31];
    const int tile   = blockIdx.y;
    if (tile >= ntiles) return;
    const int t    = ws_i[32 + tile];
    const int m0   = ws_i[128 + tile];
    const int base = ws_i[t];
    const int cntt = ws_i[t + 1] - ws_i[t];
    const int k0   = blockIdx.x * KCH;
    const int* idx = ws_i + 256;

    __shared__ short xs[TM][LDS_K];       // 32 x 136 shorts
    __shared__ short wl[C_DIM][LDS_K];    // 128 x 136 shorts

    const int tid = threadIdx.x;

    // Stage (TM + C_DIM) rows x 128 k: fp32 global -> bf16 LDS. 20 float4/thread.
    for (int f = tid; f < (TM + C_DIM) * 32; f += 256) {
        const int row = f >> 5;
        const int kf  = f & 31;
        float4 v = make_float4(0.f, 0.f, 0.f, 0.f);
        short* dst;
        if (row < TM) {
            const int r = m0 + row;
            if (r < cntt) {
                const int n = idx[base + r];
                v = *reinterpret_cast<const float4*>(x + (size_t)n * D_DIM + k0 + kf * 4);
            }
            dst = &xs[row][kf * 4];
        } else {
            const int c = row - TM;
            v = *reinterpret_cast<const float4*>(
                weights + ((size_t)t * C_DIM + c) * D_DIM + k0 + kf * 4);
            dst = &wl[c][kf * 4];
        }
        short4 sv;
        sv.x = f2bf(v.x); sv.y = f2bf(v.y); sv.z = f2bf(v.z); sv.w = f2bf(v.w);
        *reinterpret_cast<short4*>(dst) = sv;
    }
    __syncthreads();

    // 4 waves: wave (mw, nbq): mw = wid&1 -> sample rows mw*16..+15,
    //          nb = (wid>>1)*64 -> channels nb..nb+63 (4 n-fragments).
    const int wid  = tid >> 6;
    const int lane = tid & 63;
    const int mw   = wid & 1;
    const int nb   = (wid >> 1) * 64;

    const int ar   = mw * 16 + (lane & 15);   // A row (sample within tile)
    const int kl   = (lane >> 4) * 8;         // k offset within 32-k step

    f32x4 acc0 = {0.f, 0.f, 0.f, 0.f};
    f32x4 acc1 = {0.f, 0.f, 0.f, 0.f};
    f32x4 acc2 = {0.f, 0.f, 0.f, 0.f};
    f32x4 acc3 = {0.f, 0.f, 0.f, 0.f};

    #pragma unroll
    for (int ks = 0; ks < KCH / 32; ++ks) {
        const int ko = ks * 32 + kl;
        const bf16x8 a = *reinterpret_cast<const bf16x8*>(&xs[ar][ko]);
        const bf16x8 b0 = *reinterpret_cast<const bf16x8*>(&wl[nb +  0 + (lane & 15)][ko]);
        const bf16x8 b1 = *reinterpret_cast<const bf16x8*>(&wl[nb + 16 + (lane & 15)][ko]);
        const bf16x8 b2 = *reinterpret_cast<const bf16x8*>(&wl[nb + 32 + (lane & 15)][ko]);
        const bf16x8 b3 = *reinterpret_cast<const bf16x8*>(&wl[nb + 48 + (lane & 15)][ko]);
        acc0 = __builtin_amdgcn_mfma_f32_16x16x32_bf16(a, b0, acc0, 0, 0, 0);
        acc1 = __builtin_amdgcn_mfma_f32_16x16x32_bf16(a, b1, acc1, 0, 0, 0);
        acc2 = __builtin_amdgcn_mfma_f32_16x16x32_bf16(a, b2, acc2, 0, 0, 0);
        acc3 = __builtin_amdgcn_mfma_f32_16x16x32_bf16(a, b3, acc3, 0, 0, 0);
    }

    // Epilogue: C/D layout col=lane&15, row=(lane>>4)*4+reg (m89-verified).
    const int q = lane >> 4;
    #pragma unroll
    for (int nf = 0; nf < 4; ++nf) {
        const f32x4 a = (nf == 0) ? acc0 : (nf == 1) ? acc1 : (nf == 2) ? acc2 : acc3;
        const int c = nb + nf * 16 + (lane & 15);
        #pragma unroll
        for (int reg = 0; reg < 4; ++reg) {
            const int lr = mw * 16 + q * 4 + reg;   // local sample row
            const int r  = m0 + lr;
            if (r < cntt) {
                const int n = idx[base + r];
                atomicAdd(&out[(size_t)n * C_DIM + c], a[reg]);
            }
        }
    }
}

extern "C" void kernel_launch(void* const* d_in, const int* in_sizes, int n_in,
                              void* d_out, int out_size, void* d_ws, size_t ws_size,
                              hipStream_t stream) {
    const float* x       = (const float*)d_in[0];
    const int*   tasks   = (const int*)d_in[1];
    const float* weights = (const float*)d_in[2];
    const float* biases  = (const float*)d_in[3];
    float*       out     = (float*)d_out;
    const int B = in_sizes[1];

    int* ws_i = (int*)d_ws;

    prep_kernel<<<64, 256, 0, stream>>>(tasks, biases, B, ws_i, out);

    dim3 grid2(KSPLIT, MAX_TILES);
    gemm_kernel<<<grid2, 256, 0, stream>>>(x, weights, ws_i, out);
}